// Round 10
// baseline (219.170 us; speedup 1.0000x reference)
//
#include <hip/hip_runtime.h>
#include <hip/hip_bf16.h>

#define BH   512
#define NW   256
#define CC   128
#define TOK  (BH * NW)   // 131072 tokens per side

typedef __attribute__((ext_vector_type(8))) short short8;
typedef __attribute__((ext_vector_type(4))) float f32x4;
typedef __attribute__((ext_vector_type(4))) int   i32x4;
typedef __attribute__((ext_vector_type(4))) unsigned short us4;
typedef __attribute__((ext_vector_type(2))) unsigned int u32x2;
typedef unsigned short ushort_t;

static __device__ __forceinline__ f32x4 mfma16(short8 a, short8 b, f32x4 c) {
    return __builtin_amdgcn_mfma_f32_16x16x32_bf16(a, b, c, 0, 0, 0);
}

// pack 2 f32 -> 1 u32 of 2 bf16 (compiler-managed packed convert, RNE)
static __device__ __forceinline__ unsigned int pk2(float a, float b) {
    __hip_bfloat162 h = __float22bfloat162_rn(make_float2(a, b));
    return *reinterpret_cast<unsigned int*>(&h);
}
static __device__ __forceinline__ ushort_t f2bf(float f) {
    unsigned int u = __float_as_uint(f);
    u = (u + 0x7fffu + ((u >> 16) & 1u)) >> 16;
    return (ushort_t)u;
}
// raw v_exp_f32 (2^x); inputs bounded here so no range handling needed
#if __has_builtin(__builtin_amdgcn_exp2f)
static __device__ __forceinline__ float exp2_fast(float x) { return __builtin_amdgcn_exp2f(x); }
#else
static __device__ __forceinline__ float exp2_fast(float x) { return exp2f(x); }
#endif

// ---------------------------------------------------------------------------
// Kernel 0: fold LayerNorm affine into projection weights.
//   W'[o][c] = W[o][c] * gamma[c]  (bf16)
//   bias'[o] = bp[o] + sum_c beta[c] * W[o][c]   (f32)
// ---------------------------------------------------------------------------
__global__ __launch_bounds__(256)
void k_prep(const float* __restrict__ WpL, const float* __restrict__ WpR,
            const float* __restrict__ bpL, const float* __restrict__ bpR,
            const float* __restrict__ nw,  const float* __restrict__ nb,
            ushort_t* __restrict__ Wb, float* __restrict__ bias2)
{
    const int gid = blockIdx.x * 256 + threadIdx.x;  // 0..2047
    const int row = gid >> 2;                        // 0..511 = side*256 + o
    const int q   = gid & 3;
    const int side = row >> 8;
    const int o    = row & 255;
    const float* Wp = side ? WpR : WpL;
    const float* bp = side ? bpR : bpL;
    const float* wr = Wp + (size_t)o * 128 + q * 32;

    float acc = 0.f;
#pragma unroll
    for (int g = 0; g < 4; ++g) {
        const int c = q * 32 + g * 8;
        float4 wa = *(const float4*)(wr + g * 8);
        float4 wb = *(const float4*)(wr + g * 8 + 4);
        float4 ga = *(const float4*)(nw + c);
        float4 gb = *(const float4*)(nw + c + 4);
        float4 ba = *(const float4*)(nb + c);
        float4 bb = *(const float4*)(nb + c + 4);
        acc += wa.x*ba.x + wa.y*ba.y + wa.z*ba.z + wa.w*ba.w
             + wb.x*bb.x + wb.y*bb.y + wb.z*bb.z + wb.w*bb.w;
        u32x2 o0, o1;
        o0[0] = pk2(wa.x*ga.x, wa.y*ga.y);
        o0[1] = pk2(wa.z*ga.z, wa.w*ga.w);
        o1[0] = pk2(wb.x*gb.x, wb.y*gb.y);
        o1[1] = pk2(wb.z*gb.z, wb.w*gb.w);
        *(u32x2*)(Wb + (size_t)row * 128 + c)     = o0;
        *(u32x2*)(Wb + (size_t)row * 128 + c + 4) = o1;
    }
    acc += __shfl_xor(acc, 1);
    acc += __shfl_xor(acc, 2);
    if (q == 0) bias2[row] = bp[o] + acc;
}

// ---------------------------------------------------------------------------
// Kernel 1: fused LayerNorm + KV projection (affine pre-folded into W').
//   512 thr = 8 waves; tile 64 tokens x 256 features; wave = 64 tok x 32 feat.
//   ONE barrier; output stored DIRECTLY from accumulators as us4 (4
//   consecutive features per lane) — L2 write-back merges the 32B/row chunks
//   into full lines. LDS = Asm only (17.4 KB) -> 4 blocks/CU by waves.
// ---------------------------------------------------------------------------
__global__ __launch_bounds__(512)
void k_ln_proj(const float* __restrict__ featL, const float* __restrict__ featR,
               const ushort_t* __restrict__ Wb, const float* __restrict__ bias2,
               ushort_t* __restrict__ kvL,      ushort_t* __restrict__ kvR)
{
    const int side = blockIdx.y;
    const float* feat = side ? featR : featL;
    const ushort_t* W = Wb + side * 32768;          // [256][128] bf16
    const float* b2   = bias2 + side * 256;
    ushort_t*    kv   = side ? kvR : kvL;

    const int m0  = blockIdx.x * 64;
    const int tid = threadIdx.x;
    const int wid = tid >> 6, lane = tid & 63, l16 = lane & 15, lh = lane >> 4;
    const int wn  = wid * 32;                       // wave's feature slice

    __shared__ ushort_t Asm[64][136];               // LN'd activations only

    // ---- phase 0: feat loads first (HBM long pole) ----
    const int row = tid >> 3, q = tid & 7;          // 8 threads/row, 16 elems
    const float* fr = feat + (size_t)(m0 + row) * CC + q * 16;
    float x[16];
#pragma unroll
    for (int i = 0; i < 4; ++i) {
        float4 v = *(const float4*)(fr + i * 4);
        x[i*4+0]=v.x; x[i*4+1]=v.y; x[i*4+2]=v.z; x[i*4+3]=v.w;
    }

    // ---- W-fragment + bias loads (resolve under LN compute) ----
    short8 Bf[8];                                   // [kk][tn], tn=0..1
#pragma unroll
    for (int kk = 0; kk < 4; ++kk)
#pragma unroll
        for (int tn = 0; tn < 2; ++tn)
            Bf[kk*2 + tn] = *(const short8*)(W + (size_t)(wn + tn*16 + l16) * CC + kk*32 + lh*8);
    float4 bias[2];
#pragma unroll
    for (int tn = 0; tn < 2; ++tn)
        bias[tn] = *(const float4*)(b2 + wn + tn*16 + lh*4);

    // ---- LayerNorm (no affine): z = (x-mu)*rstd ----
    {
        float s = 0.f, s2 = 0.f;
#pragma unroll
        for (int i = 0; i < 16; ++i) { s += x[i]; s2 += x[i]*x[i]; }
#pragma unroll
        for (int m = 1; m < 8; m <<= 1) { s += __shfl_xor(s, m); s2 += __shfl_xor(s2, m); }
        float mu   = s * (1.f / 128.f);
        float var  = s2 * (1.f / 128.f) - mu * mu;
        float rstd = rsqrtf(var + 1e-5f);
        float a = rstd, bsh = -mu * rstd;
#pragma unroll
        for (int g = 0; g < 2; ++g) {
            i32x4 o;
#pragma unroll
            for (int k = 0; k < 4; ++k)
                o[k] = (int)pk2(x[g*8 + 2*k] * a + bsh, x[g*8 + 2*k + 1] * a + bsh);
            *(i32x4*)&Asm[row][q * 16 + g * 8] = o;
        }
    }
    __syncthreads();

    // ---- MFMA: wave = 64 tokens x 32 features; A from LDS, B from regs ----
    f32x4 acc[4][2];                                // [m-tile][n-frag]
#pragma unroll
    for (int mt = 0; mt < 4; ++mt)
#pragma unroll
        for (int tn = 0; tn < 2; ++tn)
            acc[mt][tn] = (f32x4){0.f, 0.f, 0.f, 0.f};

#pragma unroll
    for (int kk = 0; kk < 4; ++kk) {
        short8 a[4];
#pragma unroll
        for (int mt = 0; mt < 4; ++mt)
            a[mt] = *(const short8*)&Asm[mt*16 + l16][kk*32 + lh*8];
#pragma unroll
        for (int tn = 0; tn < 2; ++tn)
#pragma unroll
            for (int mt = 0; mt < 4; ++mt)
                acc[mt][tn] = mfma16(Bf[kk*2 + tn], a[mt], acc[mt][tn]); // col=token, row=feat
    }

    // ---- epilogue: bias + scale -> bf16 -> DIRECT us4 stores ----
    const float kscale = (side == 0 && wn < 128) ? 0.14426950408889634f : 1.0f;
#pragma unroll
    for (int mt = 0; mt < 4; ++mt) {
        const int token = m0 + mt*16 + l16;
#pragma unroll
        for (int tn = 0; tn < 2; ++tn) {
            const int f0 = wn + tn*16 + lh*4;
            float v0 = (acc[mt][tn][0] + bias[tn].x) * kscale;
            float v1 = (acc[mt][tn][1] + bias[tn].y) * kscale;
            float v2 = (acc[mt][tn][2] + bias[tn].z) * kscale;
            float v3 = (acc[mt][tn][3] + bias[tn].w) * kscale;
            u32x2 wv;
            wv[0] = pk2(v0, v1);
            wv[1] = pk2(v2, v3);
            *(u32x2*)(kv + (size_t)token * 256 + f0) = wv;
        }
    }
}

// ---------------------------------------------------------------------------
// Kernel 2: attention, one (n, head, dir) per block; 8 waves x 32-row stripes.
//   No-max softmax (|S| bounded): p = exp2(s) via raw v_exp_f32.
//   Denominator via ones-MFMA; kB/pL XOR slot swizzle with (row>>1)&3;
//   vT stride 280 (16B-aligned rows). LDS 49.9 KB -> 3 blocks/CU.
// ---------------------------------------------------------------------------
template<int BF16OUT>
__global__ __launch_bounds__(512, 4)
void k_attn(const ushort_t* __restrict__ kvL, const ushort_t* __restrict__ kvR,
            float* __restrict__ outFBase, ushort_t* __restrict__ outBBase)
{
    const int bx   = blockIdx.x;
    const int work = (bx & 7) * 512 + (bx >> 3);    // 4096 = 8 chunks x 512
    const int n    = work >> 3;
    const int e    = (work >> 1) & 3;
    const int dir  = work & 1;
    const ushort_t* kvA = dir ? kvR : kvL;
    const ushort_t* kvB = dir ? kvL : kvR;

    const int tid = threadIdx.x;
    const int wid = tid >> 6, lane = tid & 63, l16 = lane & 15, lh = lane >> 4;
    const int W0 = wid * 32;
    const int kcls = (l16 >> 1) & 3;                // swizzle class of this lane's rows

    __shared__ ushort_t kB[256][32];     // keys of B side, swizzled 64B rows
    __shared__ ushort_t vT[32][280];     // V transposed [c][v], 16B-aligned rows
    __shared__ ushort_t pL[8][32][32];   // wave-private P chunk, swizzled

    // ---- stage kB (swizzled: 16B slot ^= (row>>1)&3) ----
    {
        const ushort_t* src = kvB + (size_t)n * 256 * 256 + e * 32;
#pragma unroll
        for (int p = 0; p < 2; ++p) {
            int u = tid + p * 512;
            int r = u >> 2, slot = u & 3;
            *(i32x4*)&kB[r][(slot ^ ((r >> 1) & 3)) << 3] =
                *(const i32x4*)(src + (size_t)r * 256 + slot * 8);
        }
    }
    // ---- stage vT (transpose via u32 repack) ----
    {
        const ushort_t* src = kvB + (size_t)n * 256 * 256 + 128 + e * 32;
#pragma unroll
        for (int u4 = 0; u4 < 4; ++u4) {
            int unit = tid + u4 * 512;              // 2048 = 16 c-pairs x 128 v-pairs
            int cp = unit & 15, vp = unit >> 4;
            unsigned int w0 = *(const unsigned int*)(src + (size_t)(vp*2    ) * 256 + cp*2);
            unsigned int w1 = *(const unsigned int*)(src + (size_t)(vp*2 + 1) * 256 + cp*2);
            *(unsigned int*)&vT[cp*2    ][vp*2] = (w0 & 0xffffu) | (w1 << 16);
            *(unsigned int*)&vT[cp*2 + 1][vp*2] = (w0 >> 16) | (w1 & 0xffff0000u);
        }
    }
    // ---- kA fragments direct from global ----
    short8 aK[2];
#pragma unroll
    for (int tr = 0; tr < 2; ++tr)
        aK[tr] = *(const short8*)(kvA + (size_t)(n*256 + W0 + tr*16 + l16) * 256 + e*32 + lh*8);

    // ---- ones A-fragment for the denominator MFMA ----
    short8 ones;
#pragma unroll
    for (int i = 0; i < 8; ++i) ones[i] = (short)0x3F80;   // bf16 1.0

    __syncthreads();

    f32x4 oacc[2][2];
#pragma unroll
    for (int tr = 0; tr < 2; ++tr)
#pragma unroll
        for (int ct = 0; ct < 2; ++ct)
            oacc[tr][ct] = (f32x4){0.f, 0.f, 0.f, 0.f};
    f32x4 lacc[2] = {(f32x4){0.f,0.f,0.f,0.f}, (f32x4){0.f,0.f,0.f,0.f}};

#pragma unroll 2
    for (int nc = 0; nc < 8; ++nc) {
        const int vc0 = nc * 32;

        // ---- QK chunk: S[w, vc0..vc0+31] (swizzled kB read) ----
        short8 bk0 = *(const short8*)&kB[vc0      + l16][(lh ^ kcls) << 3];
        short8 bk1 = *(const short8*)&kB[vc0 + 16 + l16][(lh ^ kcls) << 3];
        f32x4 s[2][2];
#pragma unroll
        for (int tr = 0; tr < 2; ++tr) {
            s[tr][0] = mfma16(bk0, aK[tr], (f32x4){0.f,0.f,0.f,0.f});
            s[tr][1] = mfma16(bk1, aK[tr], (f32x4){0.f,0.f,0.f,0.f});
        }

        // ---- p = exp2(s); pack -> pL (swizzled, <=2-way writes) ----
#pragma unroll
        for (int tr = 0; tr < 2; ++tr) {
            const int prow = tr*16 + l16;
#pragma unroll
            for (int tc = 0; tc < 2; ++tc) {
                float p0 = exp2_fast(s[tr][tc][0]);
                float p1 = exp2_fast(s[tr][tc][1]);
                float p2 = exp2_fast(s[tr][tc][2]);
                float p3 = exp2_fast(s[tr][tc][3]);
                u32x2 w;
                w[0] = pk2(p0, p1);
                w[1] = pk2(p2, p3);
                const int sL   = 2*tc + (lh >> 1);
                const int pcol = ((sL ^ kcls) << 3) + ((lh & 1) << 2);
                *(u32x2*)&pL[wid][prow][pcol] = w;
            }
        }

        // ---- PV + denominator for this 32-wide k-slice ----
        short8 aP[2], bV[2];
#pragma unroll
        for (int tr = 0; tr < 2; ++tr)
            aP[tr] = *(const short8*)&pL[wid][tr*16 + l16][(lh ^ kcls) << 3];
#pragma unroll
        for (int ct = 0; ct < 2; ++ct)
            bV[ct] = *(const short8*)&vT[ct*16 + l16][vc0 + lh*8];
#pragma unroll
        for (int tr = 0; tr < 2; ++tr) {
#pragma unroll
            for (int ct = 0; ct < 2; ++ct)
                oacc[tr][ct] = mfma16(bV[ct], aP[tr], oacc[tr][ct]); // col=w, row=c
            lacc[tr] = mfma16(ones, aP[tr], lacc[tr]);               // col=w, row: all = sum
        }
    }

    // ---- normalize + store (denominator already per-lane complete) ----
#pragma unroll
    for (int tr = 0; tr < 2; ++tr) {
        float rinv = 1.f / lacc[tr][0];
        const int token = n * 256 + W0 + tr*16 + l16;
        if (BF16OUT) {
            ushort_t* outB = outBBase + (size_t)dir * TOK * CC;
#pragma unroll
            for (int ct = 0; ct < 2; ++ct) {
                us4 o;
#pragma unroll
                for (int j = 0; j < 4; ++j)
                    o[j] = f2bf(oacc[tr][ct][j] * rinv);
                *(us4*)(outB + (size_t)token * CC + e*32 + ct*16 + lh*4) = o;
            }
        } else {
            float* outF = outFBase + (size_t)dir * TOK * CC;
#pragma unroll
            for (int ct = 0; ct < 2; ++ct) {
                float4 o;
                o.x = oacc[tr][ct][0] * rinv;
                o.y = oacc[tr][ct][1] * rinv;
                o.z = oacc[tr][ct][2] * rinv;
                o.w = oacc[tr][ct][3] * rinv;
                *(float4*)(outF + (size_t)token * CC + e*32 + ct*16 + lh*4) = o;
            }
        }
    }
}

// ---------------------------------------------------------------------------
// Kernel 3: out projection + bias + residual -> d_out (f32).
//   MFMA operands swapped (col=token, row=feature) so the epilogue is
//   float4 feat-load + float4 store: 64B contiguous per token row.
// ---------------------------------------------------------------------------
template<int BF16IN>
__global__ __launch_bounds__(512, 4)
void k_outproj(float* __restrict__ outBase, const ushort_t* __restrict__ aoutBase,
               const float* __restrict__ featL, const float* __restrict__ featR,
               const float* __restrict__ WoL,   const float* __restrict__ WoR,
               const float* __restrict__ boL,   const float* __restrict__ boR)
{
    const int side = blockIdx.y;
    float* io = outBase + (size_t)side * TOK * CC;
    const float* feat = side ? featR : featL;
    const float* Wo   = side ? WoR   : WoL;
    const float* bo   = side ? boR   : boL;

    const int m0 = blockIdx.x * 64;
    const int tid = threadIdx.x;
    const int wid = tid >> 6, lane = tid & 63, l16 = lane & 15, lh = lane >> 4;
    const int wm = (wid >> 2) * 32;
    const int wn = (wid & 3) * 32;

    __shared__ ushort_t Asm[64][136];
    __shared__ ushort_t Wsm[128][136];

    // ---- bias fragments (float4 per n-frag) ----
    float4 bias4[2];
#pragma unroll
    for (int nt = 0; nt < 2; ++nt)
        bias4[nt] = *(const float4*)(bo + wn + nt*16 + lh*4);

#pragma unroll
    for (int i = 0; i < 8; ++i) {
        int u = tid + i * 512;
        int r = u >> 5, c4 = (u & 31) * 4;
        float4 w4 = *(const float4*)(Wo + (size_t)r * CC + c4);
        Wsm[r][c4+0] = f2bf(w4.x); Wsm[r][c4+1] = f2bf(w4.y);
        Wsm[r][c4+2] = f2bf(w4.z); Wsm[r][c4+3] = f2bf(w4.w);
    }
    if (BF16IN) {
        const ushort_t* src = aoutBase + (size_t)side * TOK * CC;
#pragma unroll
        for (int i = 0; i < 2; ++i) {
            int u = tid + i * 512;
            int r = u >> 4, c0 = (u & 15) * 8;
            *(i32x4*)&Asm[r][c0] = *(const i32x4*)(src + (size_t)(m0 + r) * CC + c0);
        }
    } else {
#pragma unroll
        for (int i = 0; i < 4; ++i) {
            int u = tid + i * 512;
            int r = u >> 5, c4 = (u & 31) * 4;
            float4 a4 = *(const float4*)(io + (size_t)(m0 + r) * CC + c4);
            Asm[r][c4+0] = f2bf(a4.x); Asm[r][c4+1] = f2bf(a4.y);
            Asm[r][c4+2] = f2bf(a4.z); Asm[r][c4+3] = f2bf(a4.w);
        }
    }
    __syncthreads();

    f32x4 acc[2][2];
#pragma unroll
    for (int tr = 0; tr < 2; ++tr)
#pragma unroll
        for (int nt = 0; nt < 2; ++nt)
            acc[tr][nt] = (f32x4){0.f, 0.f, 0.f, 0.f};

#pragma unroll
    for (int kk = 0; kk < 4; ++kk) {
        short8 a[2], b[2];
#pragma unroll
        for (int tr = 0; tr < 2; ++tr)
            a[tr] = *(const short8*)&Asm[wm + tr*16 + l16][kk*32 + lh*8];
#pragma unroll
        for (int nt = 0; nt < 2; ++nt)
            b[nt] = *(const short8*)&Wsm[wn + nt*16 + l16][kk*32 + lh*8];
#pragma unroll
        for (int tr = 0; tr < 2; ++tr)
#pragma unroll
            for (int nt = 0; nt < 2; ++nt)
                acc[tr][nt] = mfma16(b[nt], a[tr], acc[tr][nt]);  // col=token, row=feature
    }

    // ---- epilogue: float4 residual add + float4 store (64B/token row) ----
#pragma unroll
    for (int tr = 0; tr < 2; ++tr) {
        const int token = m0 + wm + tr*16 + l16;
#pragma unroll
        for (int nt = 0; nt < 2; ++nt) {
            const int f0 = wn + nt*16 + lh*4;
            float4 ff = *(const float4*)(feat + (size_t)token * CC + f0);
            float4 o;
            o.x = acc[tr][nt][0] + bias4[nt].x + ff.x;
            o.y = acc[tr][nt][1] + bias4[nt].y + ff.y;
            o.z = acc[tr][nt][2] + bias4[nt].z + ff.z;
            o.w = acc[tr][nt][3] + bias4[nt].w + ff.w;
            *(float4*)(io + (size_t)token * CC + f0) = o;
        }
    }
}

// ---------------------------------------------------------------------------
extern "C" void kernel_launch(void* const* d_in, const int* in_sizes, int n_in,
                              void* d_out, int out_size, void* d_ws, size_t ws_size,
                              hipStream_t stream)
{
    const float* featL = (const float*)d_in[0];
    const float* featR = (const float*)d_in[1];
    const float* WpL   = (const float*)d_in[2];
    const float* WpR   = (const float*)d_in[3];
    const float* bpL   = (const float*)d_in[4];
    const float* bpR   = (const float*)d_in[5];
    const float* WoL   = (const float*)d_in[6];
    const float* boL   = (const float*)d_in[7];
    const float* WoR   = (const float*)d_in[8];
    const float* boR   = (const float*)d_in[9];
    const float* nw    = (const float*)d_in[10];
    const float* nb    = (const float*)d_in[11];

    float* out = (float*)d_out;
    ushort_t* kvL = (ushort_t*)d_ws;                 // [TOK][256] bf16
    ushort_t* kvR = kvL + (size_t)TOK * 256;         // [TOK][256] bf16
    ushort_t* aout = kvR + (size_t)TOK * 256;        // [2][TOK][128] bf16 (optional)
    ushort_t* Wb  = (ushort_t*)d_out;                // W' bf16 [2][256][128]
    float* bias2  = (float*)d_out + 32768;           // bias' f32 [2][256]

    const size_t need_bf16 = (size_t)TOK * 256 * 2 * 2 + (size_t)TOK * CC * 2 * 2;
    const bool bf16path = ws_size >= need_bf16;

    k_prep<<<dim3(8), 256, 0, stream>>>(WpL, WpR, bpL, bpR, nw, nb, Wb, bias2);
    k_ln_proj<<<dim3(2048, 2), 512, 0, stream>>>(featL, featR, Wb, bias2, kvL, kvR);
    if (bf16path) {
        k_attn<1><<<dim3(4096), 512, 0, stream>>>(kvL, kvR, out, aout);
        k_outproj<1><<<dim3(TOK / 64, 2), 512, 0, stream>>>(out, aout, featL, featR,
                                                            WoL, WoR, boL, boR);
    } else {
        k_attn<0><<<dim3(4096), 512, 0, stream>>>(kvL, kvR, out, aout);
        k_outproj<0><<<dim3(TOK / 64, 2), 512, 0, stream>>>(out, aout, featL, featR,
                                                            WoL, WoR, boL, boR);
    }
}

// Round 12
// 207.466 us; speedup vs baseline: 1.0564x; 1.0564x over previous
//
#include <hip/hip_runtime.h>
#include <hip/hip_bf16.h>

#define BH   512
#define NW   256
#define CC   128
#define TOK  (BH * NW)   // 131072 tokens per side

typedef __attribute__((ext_vector_type(8))) short short8;
typedef __attribute__((ext_vector_type(4))) float f32x4;
typedef __attribute__((ext_vector_type(4))) int   i32x4;
typedef __attribute__((ext_vector_type(4))) unsigned short us4;
typedef __attribute__((ext_vector_type(2))) unsigned int u32x2;
typedef unsigned short ushort_t;

static __device__ __forceinline__ f32x4 mfma16(short8 a, short8 b, f32x4 c) {
    return __builtin_amdgcn_mfma_f32_16x16x32_bf16(a, b, c, 0, 0, 0);
}

// pack 2 f32 -> 1 u32 of 2 bf16 (compiler-managed packed convert, RNE)
static __device__ __forceinline__ unsigned int pk2(float a, float b) {
    __hip_bfloat162 h = __float22bfloat162_rn(make_float2(a, b));
    return *reinterpret_cast<unsigned int*>(&h);
}
static __device__ __forceinline__ ushort_t f2bf(float f) {
    unsigned int u = __float_as_uint(f);
    u = (u + 0x7fffu + ((u >> 16) & 1u)) >> 16;
    return (ushort_t)u;
}
// raw v_exp_f32 (2^x); inputs bounded here so no range handling needed
#if __has_builtin(__builtin_amdgcn_exp2f)
static __device__ __forceinline__ float exp2_fast(float x) { return __builtin_amdgcn_exp2f(x); }
#else
static __device__ __forceinline__ float exp2_fast(float x) { return exp2f(x); }
#endif

// ---------------------------------------------------------------------------
// Kernel 0: prep weights.
//   blocks 0-7 : W'[o][c] = Wp[o][c]*gamma[c] (bf16); bias'[o] = bp[o]+beta.Wp[o]
//   blocks 8-11: WoB = Wo (f32 -> bf16), both sides
// ---------------------------------------------------------------------------
__global__ __launch_bounds__(256)
void k_prep(const float* __restrict__ WpL, const float* __restrict__ WpR,
            const float* __restrict__ bpL, const float* __restrict__ bpR,
            const float* __restrict__ WoL, const float* __restrict__ WoR,
            const float* __restrict__ nw,  const float* __restrict__ nb,
            ushort_t* __restrict__ Wb, float* __restrict__ bias2,
            ushort_t* __restrict__ WoB)
{
    if (blockIdx.x < 8) {
        const int gid = blockIdx.x * 256 + threadIdx.x;  // 0..2047
        const int row = gid >> 2;                        // 0..511 = side*256 + o
        const int q   = gid & 3;
        const int side = row >> 8;
        const int o    = row & 255;
        const float* Wp = side ? WpR : WpL;
        const float* bp = side ? bpR : bpL;
        const float* wr = Wp + (size_t)o * 128 + q * 32;

        float acc = 0.f;
#pragma unroll
        for (int g = 0; g < 4; ++g) {
            const int c = q * 32 + g * 8;
            float4 wa = *(const float4*)(wr + g * 8);
            float4 wb = *(const float4*)(wr + g * 8 + 4);
            float4 ga = *(const float4*)(nw + c);
            float4 gb = *(const float4*)(nw + c + 4);
            float4 ba = *(const float4*)(nb + c);
            float4 bb = *(const float4*)(nb + c + 4);
            acc += wa.x*ba.x + wa.y*ba.y + wa.z*ba.z + wa.w*ba.w
                 + wb.x*bb.x + wb.y*bb.y + wb.z*bb.z + wb.w*bb.w;
            u32x2 o0, o1;
            o0[0] = pk2(wa.x*ga.x, wa.y*ga.y);
            o0[1] = pk2(wa.z*ga.z, wa.w*ga.w);
            o1[0] = pk2(wb.x*gb.x, wb.y*gb.y);
            o1[1] = pk2(wb.z*gb.z, wb.w*gb.w);
            *(u32x2*)(Wb + (size_t)row * 128 + c)     = o0;
            *(u32x2*)(Wb + (size_t)row * 128 + c + 4) = o1;
        }
        acc += __shfl_xor(acc, 1);
        acc += __shfl_xor(acc, 2);
        if (q == 0) bias2[row] = bp[o] + acc;
    } else {
        const int idx  = (blockIdx.x - 8) * 256 + threadIdx.x;  // 0..1023
        const int row2 = idx >> 2;                              // side*128 + o
        const int q    = idx & 3;
        const int side = row2 >> 7;
        const int o    = row2 & 127;
        const float* Wo = side ? WoR : WoL;
        const float* wr = Wo + (size_t)o * 128 + q * 32;
#pragma unroll
        for (int g = 0; g < 4; ++g) {
            float4 wa = *(const float4*)(wr + g * 8);
            float4 wb = *(const float4*)(wr + g * 8 + 4);
            u32x2 o0, o1;
            o0[0] = pk2(wa.x, wa.y); o0[1] = pk2(wa.z, wa.w);
            o1[0] = pk2(wb.x, wb.y); o1[1] = pk2(wb.z, wb.w);
            *(u32x2*)(WoB + (size_t)row2 * 128 + q * 32 + g * 8)     = o0;
            *(u32x2*)(WoB + (size_t)row2 * 128 + q * 32 + g * 8 + 4) = o1;
        }
    }
}

// ---------------------------------------------------------------------------
// Kernel 1: fused LayerNorm + KV projection (affine pre-folded into W').
//   512 thr = 8 waves; tile 64 tokens x 256 features; wave = 64 tok x 32 feat.
//   kvS is a SEPARATE buffer (no union) -> only 2 barriers:
//   LN->Asm | b1 | MFMA + stage kvS | b2 | coalesced copy-out.
// ---------------------------------------------------------------------------
__global__ __launch_bounds__(512)
void k_ln_proj(const float* __restrict__ featL, const float* __restrict__ featR,
               const ushort_t* __restrict__ Wb, const float* __restrict__ bias2,
               ushort_t* __restrict__ kvL,      ushort_t* __restrict__ kvR)
{
    const int side = blockIdx.y;
    const float* feat = side ? featR : featL;
    const ushort_t* W = Wb + side * 32768;          // [256][128] bf16
    const float* b2   = bias2 + side * 256;
    ushort_t*    kv   = side ? kvR : kvL;

    const int m0  = blockIdx.x * 64;
    const int tid = threadIdx.x;
    const int wid = tid >> 6, lane = tid & 63, l16 = lane & 15, lh = lane >> 4;
    const int wn  = wid * 32;                       // wave's feature slice

    __shared__ ushort_t Asm[64][136];               // LN'd activations
    __shared__ ushort_t kvS[64][260];               // staged output (pad 4)

    // ---- phase 0: feat loads first (HBM long pole) ----
    const int row = tid >> 3, q = tid & 7;          // 8 threads/row, 16 elems
    const float* fr = feat + (size_t)(m0 + row) * CC + q * 16;
    float x[16];
#pragma unroll
    for (int i = 0; i < 4; ++i) {
        float4 v = *(const float4*)(fr + i * 4);
        x[i*4+0]=v.x; x[i*4+1]=v.y; x[i*4+2]=v.z; x[i*4+3]=v.w;
    }

    // ---- W-fragment + bias loads (resolve under LN compute) ----
    short8 Bf[8];                                   // [kk][tn], tn=0..1
#pragma unroll
    for (int kk = 0; kk < 4; ++kk)
#pragma unroll
        for (int tn = 0; tn < 2; ++tn)
            Bf[kk*2 + tn] = *(const short8*)(W + (size_t)(wn + tn*16 + l16) * CC + kk*32 + lh*8);
    float4 bias[2];
#pragma unroll
    for (int tn = 0; tn < 2; ++tn)
        bias[tn] = *(const float4*)(b2 + wn + tn*16 + lh*4);

    // ---- LayerNorm (no affine): z = (x-mu)*rstd ----
    {
        float s = 0.f, s2 = 0.f;
#pragma unroll
        for (int i = 0; i < 16; ++i) { s += x[i]; s2 += x[i]*x[i]; }
#pragma unroll
        for (int m = 1; m < 8; m <<= 1) { s += __shfl_xor(s, m); s2 += __shfl_xor(s2, m); }
        float mu   = s * (1.f / 128.f);
        float var  = s2 * (1.f / 128.f) - mu * mu;
        float rstd = rsqrtf(var + 1e-5f);
        float a = rstd, bsh = -mu * rstd;
#pragma unroll
        for (int g = 0; g < 2; ++g) {
            i32x4 o;
#pragma unroll
            for (int k = 0; k < 4; ++k)
                o[k] = (int)pk2(x[g*8 + 2*k] * a + bsh, x[g*8 + 2*k + 1] * a + bsh);
            *(i32x4*)&Asm[row][q * 16 + g * 8] = o;
        }
    }
    __syncthreads();   // b1: Asm ready

    // ---- MFMA: wave = 64 tokens x 32 features; A from LDS, B from regs ----
    f32x4 acc[4][2];                                // [m-tile][n-frag]
#pragma unroll
    for (int mt = 0; mt < 4; ++mt)
#pragma unroll
        for (int tn = 0; tn < 2; ++tn)
            acc[mt][tn] = (f32x4){0.f, 0.f, 0.f, 0.f};

#pragma unroll
    for (int kk = 0; kk < 4; ++kk) {
        short8 a[4];
#pragma unroll
        for (int mt = 0; mt < 4; ++mt)
            a[mt] = *(const short8*)&Asm[mt*16 + l16][kk*32 + lh*8];
#pragma unroll
        for (int tn = 0; tn < 2; ++tn)
#pragma unroll
            for (int mt = 0; mt < 4; ++mt)
                acc[mt][tn] = mfma16(Bf[kk*2 + tn], a[mt], acc[mt][tn]); // col=token, row=feat
    }

    // ---- epilogue: bias + scale -> bf16 -> staged LDS (separate buffer) ----
    const float kscale = (side == 0 && wn < 128) ? 0.14426950408889634f : 1.0f;
#pragma unroll
    for (int mt = 0; mt < 4; ++mt)
#pragma unroll
        for (int tn = 0; tn < 2; ++tn) {
            const int r    = mt*16 + l16;                 // token-local
            const int slot = (wn >> 2) + tn*4 + lh;       // 8B slot (feature/4)
            float v0 = (acc[mt][tn][0] + bias[tn].x) * kscale;
            float v1 = (acc[mt][tn][1] + bias[tn].y) * kscale;
            float v2 = (acc[mt][tn][2] + bias[tn].z) * kscale;
            float v3 = (acc[mt][tn][3] + bias[tn].w) * kscale;
            u32x2 wv;
            wv[0] = pk2(v0, v1);
            wv[1] = pk2(v2, v3);
            *(u32x2*)&kvS[r][slot * 4] = wv;
        }
    __syncthreads();   // b2: kvS ready

    // ---- coalesced copy-out: 512B contiguous per wave-iteration ----
#pragma unroll
    for (int it = 0; it < 8; ++it) {
        int u = it * 512 + tid;
        int r = u >> 6, sl = u & 63;
        u32x2 wv = *(const u32x2*)&kvS[r][sl * 4];
        *(u32x2*)(kv + (size_t)(m0 + r) * 256 + sl * 4) = wv;
    }
}

// ---------------------------------------------------------------------------
// Kernel 2: attention, one (n, head, dir) per block; 8 waves x 32-row stripes.
//   No-max softmax (|S| bounded): p = exp2(s) via raw v_exp_f32.
//   Denominator via ones-MFMA; kB/pL XOR slot swizzle with (row>>1)&3;
//   vT stride 280 (16B-aligned rows). LDS 49.9 KB -> 3 blocks/CU.
// ---------------------------------------------------------------------------
template<int BF16OUT>
__global__ __launch_bounds__(512, 4)
void k_attn(const ushort_t* __restrict__ kvL, const ushort_t* __restrict__ kvR,
            float* __restrict__ outFBase, ushort_t* __restrict__ outBBase)
{
    const int bx   = blockIdx.x;
    const int work = (bx & 7) * 512 + (bx >> 3);    // 4096 = 8 chunks x 512
    const int n    = work >> 3;
    const int e    = (work >> 1) & 3;
    const int dir  = work & 1;
    const ushort_t* kvA = dir ? kvR : kvL;
    const ushort_t* kvB = dir ? kvL : kvR;

    const int tid = threadIdx.x;
    const int wid = tid >> 6, lane = tid & 63, l16 = lane & 15, lh = lane >> 4;
    const int W0 = wid * 32;
    const int kcls = (l16 >> 1) & 3;                // swizzle class of this lane's rows

    __shared__ ushort_t kB[256][32];     // keys of B side, swizzled 64B rows
    __shared__ ushort_t vT[32][280];     // V transposed [c][v], 16B-aligned rows
    __shared__ ushort_t pL[8][32][32];   // wave-private P chunk, swizzled

    // ---- stage kB (swizzled: 16B slot ^= (row>>1)&3) ----
    {
        const ushort_t* src = kvB + (size_t)n * 256 * 256 + e * 32;
#pragma unroll
        for (int p = 0; p < 2; ++p) {
            int u = tid + p * 512;
            int r = u >> 2, slot = u & 3;
            *(i32x4*)&kB[r][(slot ^ ((r >> 1) & 3)) << 3] =
                *(const i32x4*)(src + (size_t)r * 256 + slot * 8);
        }
    }
    // ---- stage vT (transpose via u32 repack) ----
    {
        const ushort_t* src = kvB + (size_t)n * 256 * 256 + 128 + e * 32;
#pragma unroll
        for (int u4 = 0; u4 < 4; ++u4) {
            int unit = tid + u4 * 512;              // 2048 = 16 c-pairs x 128 v-pairs
            int cp = unit & 15, vp = unit >> 4;
            unsigned int w0 = *(const unsigned int*)(src + (size_t)(vp*2    ) * 256 + cp*2);
            unsigned int w1 = *(const unsigned int*)(src + (size_t)(vp*2 + 1) * 256 + cp*2);
            *(unsigned int*)&vT[cp*2    ][vp*2] = (w0 & 0xffffu) | (w1 << 16);
            *(unsigned int*)&vT[cp*2 + 1][vp*2] = (w0 >> 16) | (w1 & 0xffff0000u);
        }
    }
    // ---- kA fragments direct from global ----
    short8 aK[2];
#pragma unroll
    for (int tr = 0; tr < 2; ++tr)
        aK[tr] = *(const short8*)(kvA + (size_t)(n*256 + W0 + tr*16 + l16) * 256 + e*32 + lh*8);

    // ---- ones A-fragment for the denominator MFMA ----
    short8 ones;
#pragma unroll
    for (int i = 0; i < 8; ++i) ones[i] = (short)0x3F80;   // bf16 1.0

    __syncthreads();

    f32x4 oacc[2][2];
#pragma unroll
    for (int tr = 0; tr < 2; ++tr)
#pragma unroll
        for (int ct = 0; ct < 2; ++ct)
            oacc[tr][ct] = (f32x4){0.f, 0.f, 0.f, 0.f};
    f32x4 lacc[2] = {(f32x4){0.f,0.f,0.f,0.f}, (f32x4){0.f,0.f,0.f,0.f}};

#pragma unroll 2
    for (int nc = 0; nc < 8; ++nc) {
        const int vc0 = nc * 32;

        // ---- QK chunk: S[w, vc0..vc0+31] (swizzled kB read) ----
        short8 bk0 = *(const short8*)&kB[vc0      + l16][(lh ^ kcls) << 3];
        short8 bk1 = *(const short8*)&kB[vc0 + 16 + l16][(lh ^ kcls) << 3];
        f32x4 s[2][2];
#pragma unroll
        for (int tr = 0; tr < 2; ++tr) {
            s[tr][0] = mfma16(bk0, aK[tr], (f32x4){0.f,0.f,0.f,0.f});
            s[tr][1] = mfma16(bk1, aK[tr], (f32x4){0.f,0.f,0.f,0.f});
        }

        // ---- p = exp2(s); pack -> pL (swizzled, <=2-way writes) ----
#pragma unroll
        for (int tr = 0; tr < 2; ++tr) {
            const int prow = tr*16 + l16;
#pragma unroll
            for (int tc = 0; tc < 2; ++tc) {
                float p0 = exp2_fast(s[tr][tc][0]);
                float p1 = exp2_fast(s[tr][tc][1]);
                float p2 = exp2_fast(s[tr][tc][2]);
                float p3 = exp2_fast(s[tr][tc][3]);
                u32x2 w;
                w[0] = pk2(p0, p1);
                w[1] = pk2(p2, p3);
                const int sL   = 2*tc + (lh >> 1);
                const int pcol = ((sL ^ kcls) << 3) + ((lh & 1) << 2);
                *(u32x2*)&pL[wid][prow][pcol] = w;
            }
        }

        // ---- PV + denominator for this 32-wide k-slice ----
        short8 aP[2], bV[2];
#pragma unroll
        for (int tr = 0; tr < 2; ++tr)
            aP[tr] = *(const short8*)&pL[wid][tr*16 + l16][(lh ^ kcls) << 3];
#pragma unroll
        for (int ct = 0; ct < 2; ++ct)
            bV[ct] = *(const short8*)&vT[ct*16 + l16][vc0 + lh*8];
#pragma unroll
        for (int tr = 0; tr < 2; ++tr) {
#pragma unroll
            for (int ct = 0; ct < 2; ++ct)
                oacc[tr][ct] = mfma16(bV[ct], aP[tr], oacc[tr][ct]); // col=w, row=c
            lacc[tr] = mfma16(ones, aP[tr], lacc[tr]);               // col=w, row: all = sum
        }
    }

    // ---- normalize + store (denominator already per-lane complete) ----
#pragma unroll
    for (int tr = 0; tr < 2; ++tr) {
        float rinv = 1.f / lacc[tr][0];
        const int token = n * 256 + W0 + tr*16 + l16;
        if (BF16OUT) {
            ushort_t* outB = outBBase + (size_t)dir * TOK * CC;
#pragma unroll
            for (int ct = 0; ct < 2; ++ct) {
                us4 o;
#pragma unroll
                for (int j = 0; j < 4; ++j)
                    o[j] = f2bf(oacc[tr][ct][j] * rinv);
                *(us4*)(outB + (size_t)token * CC + e*32 + ct*16 + lh*4) = o;
            }
        } else {
            float* outF = outFBase + (size_t)dir * TOK * CC;
#pragma unroll
            for (int ct = 0; ct < 2; ++ct) {
                float4 o;
                o.x = oacc[tr][ct][0] * rinv;
                o.y = oacc[tr][ct][1] * rinv;
                o.z = oacc[tr][ct][2] * rinv;
                o.w = oacc[tr][ct][3] * rinv;
                *(float4*)(outF + (size_t)token * CC + e*32 + ct*16 + lh*4) = o;
            }
        }
    }
}

// ---------------------------------------------------------------------------
// Kernel 3 (fast, bf16 path): out projection + bias + residual -> d_out (f32).
//   Wo held in registers (bf16, pre-converted by k_prep into d_ws scratch —
//   NOT d_out, which this kernel writes); only aout staged in LDS; ONE
//   barrier; float4 epilogue (col=token, row=feature MFMA).
// ---------------------------------------------------------------------------
__global__ __launch_bounds__(512)
void k_outproj_fast(float* __restrict__ outBase, const ushort_t* __restrict__ aoutBase,
                    const float* __restrict__ featL, const float* __restrict__ featR,
                    const ushort_t* __restrict__ WoB,
                    const float* __restrict__ boL, const float* __restrict__ boR)
{
    const int side = blockIdx.y;
    float* io = outBase + (size_t)side * TOK * CC;
    const float* feat = side ? featR : featL;
    const ushort_t* Wo = WoB + side * 16384;        // [128][128] bf16
    const float* bo   = side ? boR : boL;

    const int m0 = blockIdx.x * 64;
    const int tid = threadIdx.x;
    const int wid = tid >> 6, lane = tid & 63, l16 = lane & 15, lh = lane >> 4;
    const int wm = (wid >> 2) * 32;
    const int wn = (wid & 3) * 32;

    __shared__ ushort_t Asm[64][136];

    // ---- Wo fragments + bias in registers (L2-hot) ----
    short8 Bf[8];
#pragma unroll
    for (int kk = 0; kk < 4; ++kk)
#pragma unroll
        for (int tn = 0; tn < 2; ++tn)
            Bf[kk*2 + tn] = *(const short8*)(Wo + (size_t)(wn + tn*16 + l16) * CC + kk*32 + lh*8);
    float4 bias4[2];
#pragma unroll
    for (int nt = 0; nt < 2; ++nt)
        bias4[nt] = *(const float4*)(bo + wn + nt*16 + lh*4);

    // ---- stage aout tile (bf16, coalesced 16B) ----
    {
        const ushort_t* src = aoutBase + (size_t)side * TOK * CC;
#pragma unroll
        for (int i = 0; i < 2; ++i) {
            int u = tid + i * 512;
            int r = u >> 4, c0 = (u & 15) * 8;
            *(i32x4*)&Asm[r][c0] = *(const i32x4*)(src + (size_t)(m0 + r) * CC + c0);
        }
    }
    __syncthreads();

    f32x4 acc[2][2];
#pragma unroll
    for (int tr = 0; tr < 2; ++tr)
#pragma unroll
        for (int nt = 0; nt < 2; ++nt)
            acc[tr][nt] = (f32x4){0.f, 0.f, 0.f, 0.f};

#pragma unroll
    for (int kk = 0; kk < 4; ++kk) {
        short8 a[2];
#pragma unroll
        for (int tr = 0; tr < 2; ++tr)
            a[tr] = *(const short8*)&Asm[wm + tr*16 + l16][kk*32 + lh*8];
#pragma unroll
        for (int tr = 0; tr < 2; ++tr)
#pragma unroll
            for (int nt = 0; nt < 2; ++nt)
                acc[tr][nt] = mfma16(Bf[kk*2 + nt], a[tr], acc[tr][nt]);  // col=token, row=feature
    }

    // ---- epilogue: float4 residual add + float4 store (64B/token row) ----
#pragma unroll
    for (int tr = 0; tr < 2; ++tr) {
        const int token = m0 + wm + tr*16 + l16;
#pragma unroll
        for (int nt = 0; nt < 2; ++nt) {
            const int f0 = wn + nt*16 + lh*4;
            float4 ff = *(const float4*)(feat + (size_t)token * CC + f0);
            float4 o;
            o.x = acc[tr][nt][0] + bias4[nt].x + ff.x;
            o.y = acc[tr][nt][1] + bias4[nt].y + ff.y;
            o.z = acc[tr][nt][2] + bias4[nt].z + ff.z;
            o.w = acc[tr][nt][3] + bias4[nt].w + ff.w;
            *(float4*)(io + (size_t)token * CC + f0) = o;
        }
    }
}

// ---------------------------------------------------------------------------
// Kernel 3 (fallback, f32 attn-out in d_out): staging version, reads Wo input.
// ---------------------------------------------------------------------------
__global__ __launch_bounds__(512, 4)
void k_outproj_slow(float* __restrict__ outBase,
                    const float* __restrict__ featL, const float* __restrict__ featR,
                    const float* __restrict__ WoL,   const float* __restrict__ WoR,
                    const float* __restrict__ boL,   const float* __restrict__ boR)
{
    const int side = blockIdx.y;
    float* io = outBase + (size_t)side * TOK * CC;
    const float* feat = side ? featR : featL;
    const float* Wo   = side ? WoR   : WoL;
    const float* bo   = side ? boR   : boL;

    const int m0 = blockIdx.x * 64;
    const int tid = threadIdx.x;
    const int wid = tid >> 6, lane = tid & 63, l16 = lane & 15, lh = lane >> 4;
    const int wm = (wid >> 2) * 32;
    const int wn = (wid & 3) * 32;

    __shared__ ushort_t Asm[64][136];
    __shared__ ushort_t Wsm[128][136];

    float4 bias4[2];
#pragma unroll
    for (int nt = 0; nt < 2; ++nt)
        bias4[nt] = *(const float4*)(bo + wn + nt*16 + lh*4);

#pragma unroll
    for (int i = 0; i < 8; ++i) {
        int u = tid + i * 512;
        int r = u >> 5, c4 = (u & 31) * 4;
        float4 w4 = *(const float4*)(Wo + (size_t)r * CC + c4);
        u32x2 wv; wv[0] = pk2(w4.x, w4.y); wv[1] = pk2(w4.z, w4.w);
        *(u32x2*)&Wsm[r][c4] = wv;
    }
#pragma unroll
    for (int i = 0; i < 4; ++i) {
        int u = tid + i * 512;
        int r = u >> 5, c4 = (u & 31) * 4;
        float4 a4 = *(const float4*)(io + (size_t)(m0 + r) * CC + c4);
        u32x2 av; av[0] = pk2(a4.x, a4.y); av[1] = pk2(a4.z, a4.w);
        *(u32x2*)&Asm[r][c4] = av;
    }
    __syncthreads();

    f32x4 acc[2][2];
#pragma unroll
    for (int tr = 0; tr < 2; ++tr)
#pragma unroll
        for (int nt = 0; nt < 2; ++nt)
            acc[tr][nt] = (f32x4){0.f, 0.f, 0.f, 0.f};

#pragma unroll
    for (int kk = 0; kk < 4; ++kk) {
        short8 a[2], b[2];
#pragma unroll
        for (int tr = 0; tr < 2; ++tr)
            a[tr] = *(const short8*)&Asm[wm + tr*16 + l16][kk*32 + lh*8];
#pragma unroll
        for (int nt = 0; nt < 2; ++nt)
            b[nt] = *(const short8*)&Wsm[wn + nt*16 + l16][kk*32 + lh*8];
#pragma unroll
        for (int tr = 0; tr < 2; ++tr)
#pragma unroll
            for (int nt = 0; nt < 2; ++nt)
                acc[tr][nt] = mfma16(b[nt], a[tr], acc[tr][nt]);  // col=token, row=feature
    }

#pragma unroll
    for (int tr = 0; tr < 2; ++tr) {
        const int token = m0 + wm + tr*16 + l16;
#pragma unroll
        for (int nt = 0; nt < 2; ++nt) {
            const int f0 = wn + nt*16 + lh*4;
            float4 ff = *(const float4*)(feat + (size_t)token * CC + f0);
            float4 o;
            o.x = acc[tr][nt][0] + bias4[nt].x + ff.x;
            o.y = acc[tr][nt][1] + bias4[nt].y + ff.y;
            o.z = acc[tr][nt][2] + bias4[nt].z + ff.z;
            o.w = acc[tr][nt][3] + bias4[nt].w + ff.w;
            *(float4*)(io + (size_t)token * CC + f0) = o;
        }
    }
}

// ---------------------------------------------------------------------------
extern "C" void kernel_launch(void* const* d_in, const int* in_sizes, int n_in,
                              void* d_out, int out_size, void* d_ws, size_t ws_size,
                              hipStream_t stream)
{
    const float* featL = (const float*)d_in[0];
    const float* featR = (const float*)d_in[1];
    const float* WpL   = (const float*)d_in[2];
    const float* WpR   = (const float*)d_in[3];
    const float* bpL   = (const float*)d_in[4];
    const float* bpR   = (const float*)d_in[5];
    const float* WoL   = (const float*)d_in[6];
    const float* boL   = (const float*)d_in[7];
    const float* WoR   = (const float*)d_in[8];
    const float* boR   = (const float*)d_in[9];
    const float* nw    = (const float*)d_in[10];
    const float* nb    = (const float*)d_in[11];

    float* out = (float*)d_out;
    ushort_t* kvL = (ushort_t*)d_ws;                 // [TOK][256] bf16
    ushort_t* kvR = kvL + (size_t)TOK * 256;         // [TOK][256] bf16
    ushort_t* aout = kvR + (size_t)TOK * 256;        // [2][TOK][128] bf16

    // ws requirement: kv (134.2 MB) + aout (67.1 MB) + weight scratch (~200 KB)
    const size_t kv_us   = (size_t)TOK * 256 * 2;    // ushorts
    const size_t aout_us = (size_t)TOK * CC * 2;     // ushorts
    const size_t wscr_us = 65536 + 1024 + 32768;     // Wb + bias2(as us) + WoB
    const bool bf16path = ws_size >= (kv_us + aout_us + wscr_us) * 2;

    if (bf16path) {
        // ALL weight scratch in d_ws — k_outproj_fast writes d_out, so scratch
        // must not live there (round-11 NaN: WoB in d_out raced with io stores)
        ushort_t* Wb  = aout + aout_us;              // [2][256][128] bf16
        float* bias2  = (float*)(Wb + 65536);        // [2][256] f32
        ushort_t* WoB = (ushort_t*)(bias2 + 512);    // [2][128][128] bf16

        k_prep<<<dim3(12), 256, 0, stream>>>(WpL, WpR, bpL, bpR, WoL, WoR,
                                             nw, nb, Wb, bias2, WoB);
        k_ln_proj<<<dim3(2048, 2), 512, 0, stream>>>(featL, featR, Wb, bias2, kvL, kvR);
        k_attn<1><<<dim3(4096), 512, 0, stream>>>(kvL, kvR, out, aout);
        k_outproj_fast<<<dim3(TOK / 64, 2), 512, 0, stream>>>(out, aout, featL, featR,
                                                              WoB, boL, boR);
    } else {
        // fallback: Wb/bias2 in d_out is safe here — its only reader
        // (k_ln_proj) finishes before the first d_out writer (k_attn<0>)
        ushort_t* Wb  = (ushort_t*)d_out;            // [2][256][128] bf16
        float* bias2  = (float*)d_out + 32768;       // [2][256] f32
        ushort_t* WoB = (ushort_t*)d_out + 66560;    // written, never read

        k_prep<<<dim3(12), 256, 0, stream>>>(WpL, WpR, bpL, bpR, WoL, WoR,
                                             nw, nb, Wb, bias2, WoB);
        k_ln_proj<<<dim3(2048, 2), 512, 0, stream>>>(featL, featR, Wb, bias2, kvL, kvR);
        k_attn<0><<<dim3(4096), 512, 0, stream>>>(kvL, kvR, out, aout);
        k_outproj_slow<<<dim3(TOK / 64, 2), 512, 0, stream>>>(out, featL, featR,
                                                              WoL, WoR, boL, boR);
    }
}

// Round 13
// 196.733 us; speedup vs baseline: 1.1140x; 1.0546x over previous
//
#include <hip/hip_runtime.h>
#include <hip/hip_bf16.h>

#define BH   512
#define NW   256
#define CC   128
#define TOK  (BH * NW)   // 131072 tokens per side

typedef __attribute__((ext_vector_type(8))) short short8;
typedef __attribute__((ext_vector_type(4))) float f32x4;
typedef __attribute__((ext_vector_type(4))) int   i32x4;
typedef __attribute__((ext_vector_type(4))) unsigned short us4;
typedef __attribute__((ext_vector_type(2))) unsigned int u32x2;
typedef unsigned short ushort_t;

static __device__ __forceinline__ f32x4 mfma16(short8 a, short8 b, f32x4 c) {
    return __builtin_amdgcn_mfma_f32_16x16x32_bf16(a, b, c, 0, 0, 0);
}

// pack 2 f32 -> 1 u32 of 2 bf16 (compiler-managed packed convert, RNE)
static __device__ __forceinline__ unsigned int pk2(float a, float b) {
    __hip_bfloat162 h = __float22bfloat162_rn(make_float2(a, b));
    return *reinterpret_cast<unsigned int*>(&h);
}
static __device__ __forceinline__ ushort_t f2bf(float f) {
    unsigned int u = __float_as_uint(f);
    u = (u + 0x7fffu + ((u >> 16) & 1u)) >> 16;
    return (ushort_t)u;
}
// raw v_exp_f32 (2^x); inputs bounded here so no range handling needed
#if __has_builtin(__builtin_amdgcn_exp2f)
static __device__ __forceinline__ float exp2_fast(float x) { return __builtin_amdgcn_exp2f(x); }
#else
static __device__ __forceinline__ float exp2_fast(float x) { return exp2f(x); }
#endif

// ---------------------------------------------------------------------------
// Kernel 0: prep weights.
//   blocks 0-7 : W'[o][c] = Wp[o][c]*gamma[c] (bf16); bias'[o] = bp[o]+beta.Wp[o]
//   blocks 8-11: WoB = Wo (f32 -> bf16), both sides
// ---------------------------------------------------------------------------
__global__ __launch_bounds__(256)
void k_prep(const float* __restrict__ WpL, const float* __restrict__ WpR,
            const float* __restrict__ bpL, const float* __restrict__ bpR,
            const float* __restrict__ WoL, const float* __restrict__ WoR,
            const float* __restrict__ nw,  const float* __restrict__ nb,
            ushort_t* __restrict__ Wb, float* __restrict__ bias2,
            ushort_t* __restrict__ WoB)
{
    if (blockIdx.x < 8) {
        const int gid = blockIdx.x * 256 + threadIdx.x;  // 0..2047
        const int row = gid >> 2;                        // 0..511 = side*256 + o
        const int q   = gid & 3;
        const int side = row >> 8;
        const int o    = row & 255;
        const float* Wp = side ? WpR : WpL;
        const float* bp = side ? bpR : bpL;
        const float* wr = Wp + (size_t)o * 128 + q * 32;

        float acc = 0.f;
#pragma unroll
        for (int g = 0; g < 4; ++g) {
            const int c = q * 32 + g * 8;
            float4 wa = *(const float4*)(wr + g * 8);
            float4 wb = *(const float4*)(wr + g * 8 + 4);
            float4 ga = *(const float4*)(nw + c);
            float4 gb = *(const float4*)(nw + c + 4);
            float4 ba = *(const float4*)(nb + c);
            float4 bb = *(const float4*)(nb + c + 4);
            acc += wa.x*ba.x + wa.y*ba.y + wa.z*ba.z + wa.w*ba.w
                 + wb.x*bb.x + wb.y*bb.y + wb.z*bb.z + wb.w*bb.w;
            u32x2 o0, o1;
            o0[0] = pk2(wa.x*ga.x, wa.y*ga.y);
            o0[1] = pk2(wa.z*ga.z, wa.w*ga.w);
            o1[0] = pk2(wb.x*gb.x, wb.y*gb.y);
            o1[1] = pk2(wb.z*gb.z, wb.w*gb.w);
            *(u32x2*)(Wb + (size_t)row * 128 + c)     = o0;
            *(u32x2*)(Wb + (size_t)row * 128 + c + 4) = o1;
        }
        acc += __shfl_xor(acc, 1);
        acc += __shfl_xor(acc, 2);
        if (q == 0) bias2[row] = bp[o] + acc;
    } else {
        const int idx  = (blockIdx.x - 8) * 256 + threadIdx.x;  // 0..1023
        const int row2 = idx >> 2;                              // side*128 + o
        const int q    = idx & 3;
        const int side = row2 >> 7;
        const int o    = row2 & 127;
        const float* Wo = side ? WoR : WoL;
        const float* wr = Wo + (size_t)o * 128 + q * 32;
#pragma unroll
        for (int g = 0; g < 4; ++g) {
            float4 wa = *(const float4*)(wr + g * 8);
            float4 wb = *(const float4*)(wr + g * 8 + 4);
            u32x2 o0, o1;
            o0[0] = pk2(wa.x, wa.y); o0[1] = pk2(wa.z, wa.w);
            o1[0] = pk2(wb.x, wb.y); o1[1] = pk2(wb.z, wb.w);
            *(u32x2*)(WoB + (size_t)row2 * 128 + q * 32 + g * 8)     = o0;
            *(u32x2*)(WoB + (size_t)row2 * 128 + q * 32 + g * 8 + 4) = o1;
        }
    }
}

// ---------------------------------------------------------------------------
// Kernel 1: fused LayerNorm + KV projection (affine pre-folded into W').
//   PERSISTENT over 4 tiles of 64 tokens: W'/bias loaded once per block;
//   feat(t+1) prefetched (issued after b1) while MFMA/epilogue/copy-out of
//   tile t run. 2 barriers per tile. grid (512, 2), 512 thr.
// ---------------------------------------------------------------------------
__global__ __launch_bounds__(512)
void k_ln_proj(const float* __restrict__ featL, const float* __restrict__ featR,
               const ushort_t* __restrict__ Wb, const float* __restrict__ bias2,
               ushort_t* __restrict__ kvL,      ushort_t* __restrict__ kvR)
{
    const int side = blockIdx.y;
    const float* feat = side ? featR : featL;
    const ushort_t* W = Wb + side * 32768;          // [256][128] bf16
    const float* b2   = bias2 + side * 256;
    ushort_t*    kv   = side ? kvR : kvL;

    const int tile0 = blockIdx.x * 4;
    const int tid = threadIdx.x;
    const int wid = tid >> 6, lane = tid & 63, l16 = lane & 15, lh = lane >> 4;
    const int wn  = wid * 32;                       // wave's feature slice

    __shared__ ushort_t Asm[64][136];               // LN'd activations
    __shared__ ushort_t kvS[64][260];               // staged output (pad 4)

    const int row = tid >> 3, q = tid & 7;          // 8 threads/row, 16 elems

    // ---- prologue: feat(tile 0) loads first (HBM long pole) ----
    float xc[16], xn[16];
    {
        const float* fr = feat + (size_t)(tile0 * 64 + row) * CC + q * 16;
#pragma unroll
        for (int i = 0; i < 4; ++i) {
            float4 v = *(const float4*)(fr + i * 4);
            xc[i*4+0]=v.x; xc[i*4+1]=v.y; xc[i*4+2]=v.z; xc[i*4+3]=v.w;
        }
    }

    // ---- W-fragment + bias loads ONCE per block ----
    short8 Bf[8];                                   // [kk][tn], tn=0..1
#pragma unroll
    for (int kk = 0; kk < 4; ++kk)
#pragma unroll
        for (int tn = 0; tn < 2; ++tn)
            Bf[kk*2 + tn] = *(const short8*)(W + (size_t)(wn + tn*16 + l16) * CC + kk*32 + lh*8);
    float4 bias[2];
#pragma unroll
    for (int tn = 0; tn < 2; ++tn)
        bias[tn] = *(const float4*)(b2 + wn + tn*16 + lh*4);

    const float kscale = (side == 0 && wn < 128) ? 0.14426950408889634f : 1.0f;

#pragma unroll
    for (int t = 0; t < 4; ++t) {
        const int m0 = (tile0 + t) * 64;

        // ---- LayerNorm (no affine): z = (x-mu)*rstd -> Asm ----
        {
            float s = 0.f, s2 = 0.f;
#pragma unroll
            for (int i = 0; i < 16; ++i) { s += xc[i]; s2 += xc[i]*xc[i]; }
#pragma unroll
            for (int m = 1; m < 8; m <<= 1) { s += __shfl_xor(s, m); s2 += __shfl_xor(s2, m); }
            float mu   = s * (1.f / 128.f);
            float var  = s2 * (1.f / 128.f) - mu * mu;
            float rstd = rsqrtf(var + 1e-5f);
            float a = rstd, bsh = -mu * rstd;
#pragma unroll
            for (int g = 0; g < 2; ++g) {
                i32x4 o;
#pragma unroll
                for (int k = 0; k < 4; ++k)
                    o[k] = (int)pk2(xc[g*8 + 2*k] * a + bsh, xc[g*8 + 2*k + 1] * a + bsh);
                *(i32x4*)&Asm[row][q * 16 + g * 8] = o;
            }
        }
        __syncthreads();   // b1: Asm ready

        // ---- prefetch feat(t+1): in flight during MFMA/epilogue/copy-out ----
        if (t < 3) {
            const float* fr = feat + (size_t)(m0 + 64 + row) * CC + q * 16;
#pragma unroll
            for (int i = 0; i < 4; ++i) {
                float4 v = *(const float4*)(fr + i * 4);
                xn[i*4+0]=v.x; xn[i*4+1]=v.y; xn[i*4+2]=v.z; xn[i*4+3]=v.w;
            }
        }

        // ---- MFMA: wave = 64 tokens x 32 features; A from LDS, B from regs ----
        f32x4 acc[4][2];                            // [m-tile][n-frag]
#pragma unroll
        for (int mt = 0; mt < 4; ++mt)
#pragma unroll
            for (int tn = 0; tn < 2; ++tn)
                acc[mt][tn] = (f32x4){0.f, 0.f, 0.f, 0.f};

#pragma unroll
        for (int kk = 0; kk < 4; ++kk) {
            short8 a[4];
#pragma unroll
            for (int mt = 0; mt < 4; ++mt)
                a[mt] = *(const short8*)&Asm[mt*16 + l16][kk*32 + lh*8];
#pragma unroll
            for (int tn = 0; tn < 2; ++tn)
#pragma unroll
                for (int mt = 0; mt < 4; ++mt)
                    acc[mt][tn] = mfma16(Bf[kk*2 + tn], a[mt], acc[mt][tn]); // col=token, row=feat
        }

        // ---- epilogue: bias + scale -> bf16 -> staged LDS ----
#pragma unroll
        for (int mt = 0; mt < 4; ++mt)
#pragma unroll
            for (int tn = 0; tn < 2; ++tn) {
                const int r    = mt*16 + l16;             // token-local
                const int slot = (wn >> 2) + tn*4 + lh;   // 8B slot (feature/4)
                float v0 = (acc[mt][tn][0] + bias[tn].x) * kscale;
                float v1 = (acc[mt][tn][1] + bias[tn].y) * kscale;
                float v2 = (acc[mt][tn][2] + bias[tn].z) * kscale;
                float v3 = (acc[mt][tn][3] + bias[tn].w) * kscale;
                u32x2 wv;
                wv[0] = pk2(v0, v1);
                wv[1] = pk2(v2, v3);
                *(u32x2*)&kvS[r][slot * 4] = wv;
            }
        __syncthreads();   // b2: kvS ready (also guards Asm reuse next iter)

        // ---- coalesced copy-out: 512B contiguous per wave-iteration ----
#pragma unroll
        for (int it = 0; it < 8; ++it) {
            int u = it * 512 + tid;
            int r = u >> 6, sl = u & 63;
            u32x2 wv = *(const u32x2*)&kvS[r][sl * 4];
            *(u32x2*)(kv + (size_t)(m0 + r) * 256 + sl * 4) = wv;
        }

        if (t < 3) {
#pragma unroll
            for (int i = 0; i < 16; ++i) xc[i] = xn[i];
        }
    }
}

// ---------------------------------------------------------------------------
// Kernel 2: attention, one (n, head, dir) per block; 8 waves x 32-row stripes.
//   No-max softmax (|S| bounded): p = exp2(s) via raw v_exp_f32.
//   Denominator via ones-MFMA; kB/pL XOR slot swizzle with (row>>1)&3;
//   vT stride 280 (16B-aligned rows). LDS 49.9 KB -> 3 blocks/CU.
// ---------------------------------------------------------------------------
template<int BF16OUT>
__global__ __launch_bounds__(512, 4)
void k_attn(const ushort_t* __restrict__ kvL, const ushort_t* __restrict__ kvR,
            float* __restrict__ outFBase, ushort_t* __restrict__ outBBase)
{
    const int bx   = blockIdx.x;
    const int work = (bx & 7) * 512 + (bx >> 3);    // 4096 = 8 chunks x 512
    const int n    = work >> 3;
    const int e    = (work >> 1) & 3;
    const int dir  = work & 1;
    const ushort_t* kvA = dir ? kvR : kvL;
    const ushort_t* kvB = dir ? kvL : kvR;

    const int tid = threadIdx.x;
    const int wid = tid >> 6, lane = tid & 63, l16 = lane & 15, lh = lane >> 4;
    const int W0 = wid * 32;
    const int kcls = (l16 >> 1) & 3;                // swizzle class of this lane's rows

    __shared__ ushort_t kB[256][32];     // keys of B side, swizzled 64B rows
    __shared__ ushort_t vT[32][280];     // V transposed [c][v], 16B-aligned rows
    __shared__ ushort_t pL[8][32][32];   // wave-private P chunk, swizzled

    // ---- stage kB (swizzled: 16B slot ^= (row>>1)&3) ----
    {
        const ushort_t* src = kvB + (size_t)n * 256 * 256 + e * 32;
#pragma unroll
        for (int p = 0; p < 2; ++p) {
            int u = tid + p * 512;
            int r = u >> 2, slot = u & 3;
            *(i32x4*)&kB[r][(slot ^ ((r >> 1) & 3)) << 3] =
                *(const i32x4*)(src + (size_t)r * 256 + slot * 8);
        }
    }
    // ---- stage vT (transpose via u32 repack) ----
    {
        const ushort_t* src = kvB + (size_t)n * 256 * 256 + 128 + e * 32;
#pragma unroll
        for (int u4 = 0; u4 < 4; ++u4) {
            int unit = tid + u4 * 512;              // 2048 = 16 c-pairs x 128 v-pairs
            int cp = unit & 15, vp = unit >> 4;
            unsigned int w0 = *(const unsigned int*)(src + (size_t)(vp*2    ) * 256 + cp*2);
            unsigned int w1 = *(const unsigned int*)(src + (size_t)(vp*2 + 1) * 256 + cp*2);
            *(unsigned int*)&vT[cp*2    ][vp*2] = (w0 & 0xffffu) | (w1 << 16);
            *(unsigned int*)&vT[cp*2 + 1][vp*2] = (w0 >> 16) | (w1 & 0xffff0000u);
        }
    }
    // ---- kA fragments direct from global ----
    short8 aK[2];
#pragma unroll
    for (int tr = 0; tr < 2; ++tr)
        aK[tr] = *(const short8*)(kvA + (size_t)(n*256 + W0 + tr*16 + l16) * 256 + e*32 + lh*8);

    // ---- ones A-fragment for the denominator MFMA ----
    short8 ones;
#pragma unroll
    for (int i = 0; i < 8; ++i) ones[i] = (short)0x3F80;   // bf16 1.0

    __syncthreads();

    f32x4 oacc[2][2];
#pragma unroll
    for (int tr = 0; tr < 2; ++tr)
#pragma unroll
        for (int ct = 0; ct < 2; ++ct)
            oacc[tr][ct] = (f32x4){0.f, 0.f, 0.f, 0.f};
    f32x4 lacc[2] = {(f32x4){0.f,0.f,0.f,0.f}, (f32x4){0.f,0.f,0.f,0.f}};

#pragma unroll 2
    for (int nc = 0; nc < 8; ++nc) {
        const int vc0 = nc * 32;

        // ---- QK chunk: S[w, vc0..vc0+31] (swizzled kB read) ----
        short8 bk0 = *(const short8*)&kB[vc0      + l16][(lh ^ kcls) << 3];
        short8 bk1 = *(const short8*)&kB[vc0 + 16 + l16][(lh ^ kcls) << 3];
        f32x4 s[2][2];
#pragma unroll
        for (int tr = 0; tr < 2; ++tr) {
            s[tr][0] = mfma16(bk0, aK[tr], (f32x4){0.f,0.f,0.f,0.f});
            s[tr][1] = mfma16(bk1, aK[tr], (f32x4){0.f,0.f,0.f,0.f});
        }

        // ---- p = exp2(s); pack -> pL (swizzled, <=2-way writes) ----
#pragma unroll
        for (int tr = 0; tr < 2; ++tr) {
            const int prow = tr*16 + l16;
#pragma unroll
            for (int tc = 0; tc < 2; ++tc) {
                float p0 = exp2_fast(s[tr][tc][0]);
                float p1 = exp2_fast(s[tr][tc][1]);
                float p2 = exp2_fast(s[tr][tc][2]);
                float p3 = exp2_fast(s[tr][tc][3]);
                u32x2 w;
                w[0] = pk2(p0, p1);
                w[1] = pk2(p2, p3);
                const int sL   = 2*tc + (lh >> 1);
                const int pcol = ((sL ^ kcls) << 3) + ((lh & 1) << 2);
                *(u32x2*)&pL[wid][prow][pcol] = w;
            }
        }

        // ---- PV + denominator for this 32-wide k-slice ----
        short8 aP[2], bV[2];
#pragma unroll
        for (int tr = 0; tr < 2; ++tr)
            aP[tr] = *(const short8*)&pL[wid][tr*16 + l16][(lh ^ kcls) << 3];
#pragma unroll
        for (int ct = 0; ct < 2; ++ct)
            bV[ct] = *(const short8*)&vT[ct*16 + l16][vc0 + lh*8];
#pragma unroll
        for (int tr = 0; tr < 2; ++tr) {
#pragma unroll
            for (int ct = 0; ct < 2; ++ct)
                oacc[tr][ct] = mfma16(bV[ct], aP[tr], oacc[tr][ct]); // col=w, row=c
            lacc[tr] = mfma16(ones, aP[tr], lacc[tr]);               // col=w, row: all = sum
        }
    }

    // ---- normalize + store (denominator already per-lane complete) ----
#pragma unroll
    for (int tr = 0; tr < 2; ++tr) {
        float rinv = 1.f / lacc[tr][0];
        const int token = n * 256 + W0 + tr*16 + l16;
        if (BF16OUT) {
            ushort_t* outB = outBBase + (size_t)dir * TOK * CC;
#pragma unroll
            for (int ct = 0; ct < 2; ++ct) {
                us4 o;
#pragma unroll
                for (int j = 0; j < 4; ++j)
                    o[j] = f2bf(oacc[tr][ct][j] * rinv);
                *(us4*)(outB + (size_t)token * CC + e*32 + ct*16 + lh*4) = o;
            }
        } else {
            float* outF = outFBase + (size_t)dir * TOK * CC;
#pragma unroll
            for (int ct = 0; ct < 2; ++ct) {
                float4 o;
                o.x = oacc[tr][ct][0] * rinv;
                o.y = oacc[tr][ct][1] * rinv;
                o.z = oacc[tr][ct][2] * rinv;
                o.w = oacc[tr][ct][3] * rinv;
                *(float4*)(outF + (size_t)token * CC + e*32 + ct*16 + lh*4) = o;
            }
        }
    }
}

// ---------------------------------------------------------------------------
// Kernel 3 (fast, bf16 path): out projection + bias + residual -> d_out (f32).
//   PERSISTENT over 4 tiles; Wo/bias in registers once per block; Asm
//   DOUBLE-BUFFERED -> ONE barrier per tile; aout(t+1) prefetched after the
//   barrier so it flies under MFMA+epilogue. grid (512, 2), 512 thr.
// ---------------------------------------------------------------------------
__global__ __launch_bounds__(512)
void k_outproj_fast(float* __restrict__ outBase, const ushort_t* __restrict__ aoutBase,
                    const float* __restrict__ featL, const float* __restrict__ featR,
                    const ushort_t* __restrict__ WoB,
                    const float* __restrict__ boL, const float* __restrict__ boR)
{
    const int side = blockIdx.y;
    float* io = outBase + (size_t)side * TOK * CC;
    const float* feat = side ? featR : featL;
    const ushort_t* Wo = WoB + side * 16384;        // [128][128] bf16
    const float* bo   = side ? boR : boL;
    const ushort_t* src = aoutBase + (size_t)side * TOK * CC;

    const int tile0 = blockIdx.x * 4;
    const int tid = threadIdx.x;
    const int wid = tid >> 6, lane = tid & 63, l16 = lane & 15, lh = lane >> 4;
    const int wm = (wid >> 2) * 32;
    const int wn = (wid & 3) * 32;

    __shared__ ushort_t Asm[2][64][136];            // double-buffered staging

    // ---- Wo fragments + bias in registers (once per block) ----
    short8 Bf[8];
#pragma unroll
    for (int kk = 0; kk < 4; ++kk)
#pragma unroll
        for (int tn = 0; tn < 2; ++tn)
            Bf[kk*2 + tn] = *(const short8*)(Wo + (size_t)(wn + tn*16 + l16) * CC + kk*32 + lh*8);
    float4 bias4[2];
#pragma unroll
    for (int nt = 0; nt < 2; ++nt)
        bias4[nt] = *(const float4*)(bo + wn + nt*16 + lh*4);

    // ---- prologue: aout(tile 0) into registers ----
    i32x4 aReg[2];
#pragma unroll
    for (int i = 0; i < 2; ++i) {
        int u = tid + i * 512;
        int r = u >> 4, c0 = (u & 15) * 8;
        aReg[i] = *(const i32x4*)(src + (size_t)(tile0 * 64 + r) * CC + c0);
    }

#pragma unroll
    for (int t = 0; t < 4; ++t) {
        const int m0 = (tile0 + t) * 64;
        const int p  = t & 1;

        // ---- commit aout(t) regs -> Asm[p] ----
#pragma unroll
        for (int i = 0; i < 2; ++i) {
            int u = tid + i * 512;
            int r = u >> 4, c0 = (u & 15) * 8;
            *(i32x4*)&Asm[p][r][c0] = aReg[i];
        }
        __syncthreads();   // single barrier: Asm[p] ready for all waves

        // ---- prefetch aout(t+1): in flight during MFMA + epilogue ----
        if (t < 3) {
#pragma unroll
            for (int i = 0; i < 2; ++i) {
                int u = tid + i * 512;
                int r = u >> 4, c0 = (u & 15) * 8;
                aReg[i] = *(const i32x4*)(src + (size_t)(m0 + 64 + r) * CC + c0);
            }
        }
        // ---- feat loads for this tile (consumed in epilogue) ----
        float4 ff[2][2];
#pragma unroll
        for (int tr = 0; tr < 2; ++tr)
#pragma unroll
            for (int nt = 0; nt < 2; ++nt)
                ff[tr][nt] = *(const float4*)(feat + (size_t)(m0 + wm + tr*16 + l16) * CC
                                              + wn + nt*16 + lh*4);

        // ---- MFMA (col=token, row=feature) ----
        f32x4 acc[2][2];
#pragma unroll
        for (int tr = 0; tr < 2; ++tr)
#pragma unroll
            for (int nt = 0; nt < 2; ++nt)
                acc[tr][nt] = (f32x4){0.f, 0.f, 0.f, 0.f};

#pragma unroll
        for (int kk = 0; kk < 4; ++kk) {
            short8 a[2];
#pragma unroll
            for (int tr = 0; tr < 2; ++tr)
                a[tr] = *(const short8*)&Asm[p][wm + tr*16 + l16][kk*32 + lh*8];
#pragma unroll
            for (int tr = 0; tr < 2; ++tr)
#pragma unroll
                for (int nt = 0; nt < 2; ++nt)
                    acc[tr][nt] = mfma16(Bf[kk*2 + nt], a[tr], acc[tr][nt]);
        }

        // ---- epilogue: float4 residual add + float4 store (64B/token row) ----
#pragma unroll
        for (int tr = 0; tr < 2; ++tr) {
            const int token = m0 + wm + tr*16 + l16;
#pragma unroll
            for (int nt = 0; nt < 2; ++nt) {
                const int f0 = wn + nt*16 + lh*4;
                float4 o;
                o.x = acc[tr][nt][0] + bias4[nt].x + ff[tr][nt].x;
                o.y = acc[tr][nt][1] + bias4[nt].y + ff[tr][nt].y;
                o.z = acc[tr][nt][2] + bias4[nt].z + ff[tr][nt].z;
                o.w = acc[tr][nt][3] + bias4[nt].w + ff[tr][nt].w;
                *(float4*)(io + (size_t)token * CC + f0) = o;
            }
        }
        // no trailing barrier: next iter writes Asm[p^1], disjoint from Asm[p]
    }
}

// ---------------------------------------------------------------------------
// Kernel 3 (fallback, f32 attn-out in d_out): staging version, reads Wo input.
// ---------------------------------------------------------------------------
__global__ __launch_bounds__(512, 4)
void k_outproj_slow(float* __restrict__ outBase,
                    const float* __restrict__ featL, const float* __restrict__ featR,
                    const float* __restrict__ WoL,   const float* __restrict__ WoR,
                    const float* __restrict__ boL,   const float* __restrict__ boR)
{
    const int side = blockIdx.y;
    float* io = outBase + (size_t)side * TOK * CC;
    const float* feat = side ? featR : featL;
    const float* Wo   = side ? WoR   : WoL;
    const float* bo   = side ? boR   : boL;

    const int m0 = blockIdx.x * 64;
    const int tid = threadIdx.x;
    const int wid = tid >> 6, lane = tid & 63, l16 = lane & 15, lh = lane >> 4;
    const int wm = (wid >> 2) * 32;
    const int wn = (wid & 3) * 32;

    __shared__ ushort_t Asm[64][136];
    __shared__ ushort_t Wsm[128][136];

    float4 bias4[2];
#pragma unroll
    for (int nt = 0; nt < 2; ++nt)
        bias4[nt] = *(const float4*)(bo + wn + nt*16 + lh*4);

#pragma unroll
    for (int i = 0; i < 8; ++i) {
        int u = tid + i * 512;
        int r = u >> 5, c4 = (u & 31) * 4;
        float4 w4 = *(const float4*)(Wo + (size_t)r * CC + c4);
        u32x2 wv; wv[0] = pk2(w4.x, w4.y); wv[1] = pk2(w4.z, w4.w);
        *(u32x2*)&Wsm[r][c4] = wv;
    }
#pragma unroll
    for (int i = 0; i < 4; ++i) {
        int u = tid + i * 512;
        int r = u >> 5, c4 = (u & 31) * 4;
        float4 a4 = *(const float4*)(io + (size_t)(m0 + r) * CC + c4);
        u32x2 av; av[0] = pk2(a4.x, a4.y); av[1] = pk2(a4.z, a4.w);
        *(u32x2*)&Asm[r][c4] = av;
    }
    __syncthreads();

    f32x4 acc[2][2];
#pragma unroll
    for (int tr = 0; tr < 2; ++tr)
#pragma unroll
        for (int nt = 0; nt < 2; ++nt)
            acc[tr][nt] = (f32x4){0.f, 0.f, 0.f, 0.f};

#pragma unroll
    for (int kk = 0; kk < 4; ++kk) {
        short8 a[2], b[2];
#pragma unroll
        for (int tr = 0; tr < 2; ++tr)
            a[tr] = *(const short8*)&Asm[wm + tr*16 + l16][kk*32 + lh*8];
#pragma unroll
        for (int nt = 0; nt < 2; ++nt)
            b[nt] = *(const short8*)&Wsm[wn + nt*16 + l16][kk*32 + lh*8];
#pragma unroll
        for (int tr = 0; tr < 2; ++tr)
#pragma unroll
            for (int nt = 0; nt < 2; ++nt)
                acc[tr][nt] = mfma16(b[nt], a[tr], acc[tr][nt]);  // col=token, row=feature
    }

#pragma unroll
    for (int tr = 0; tr < 2; ++tr) {
        const int token = m0 + wm + tr*16 + l16;
#pragma unroll
        for (int nt = 0; nt < 2; ++nt) {
            const int f0 = wn + nt*16 + lh*4;
            float4 ff = *(const float4*)(feat + (size_t)token * CC + f0);
            float4 o;
            o.x = acc[tr][nt][0] + bias4[nt].x + ff.x;
            o.y = acc[tr][nt][1] + bias4[nt].y + ff.y;
            o.z = acc[tr][nt][2] + bias4[nt].z + ff.z;
            o.w = acc[tr][nt][3] + bias4[nt].w + ff.w;
            *(float4*)(io + (size_t)token * CC + f0) = o;
        }
    }
}

// ---------------------------------------------------------------------------
extern "C" void kernel_launch(void* const* d_in, const int* in_sizes, int n_in,
                              void* d_out, int out_size, void* d_ws, size_t ws_size,
                              hipStream_t stream)
{
    const float* featL = (const float*)d_in[0];
    const float* featR = (const float*)d_in[1];
    const float* WpL   = (const float*)d_in[2];
    const float* WpR   = (const float*)d_in[3];
    const float* bpL   = (const float*)d_in[4];
    const float* bpR   = (const float*)d_in[5];
    const float* WoL   = (const float*)d_in[6];
    const float* boL   = (const float*)d_in[7];
    const float* WoR   = (const float*)d_in[8];
    const float* boR   = (const float*)d_in[9];
    const float* nw    = (const float*)d_in[10];
    const float* nb    = (const float*)d_in[11];

    float* out = (float*)d_out;
    ushort_t* kvL = (ushort_t*)d_ws;                 // [TOK][256] bf16
    ushort_t* kvR = kvL + (size_t)TOK * 256;         // [TOK][256] bf16
    ushort_t* aout = kvR + (size_t)TOK * 256;        // [2][TOK][128] bf16

    // ws requirement: kv (134.2 MB) + aout (67.1 MB) + weight scratch (~200 KB)
    const size_t kv_us   = (size_t)TOK * 256 * 2;    // ushorts
    const size_t aout_us = (size_t)TOK * CC * 2;     // ushorts
    const size_t wscr_us = 65536 + 1024 + 32768;     // Wb + bias2(as us) + WoB
    const bool bf16path = ws_size >= (kv_us + aout_us + wscr_us) * 2;

    if (bf16path) {
        // ALL weight scratch in d_ws — k_outproj_fast writes d_out, so scratch
        // must not live there (round-11 NaN: WoB in d_out raced with io stores)
        ushort_t* Wb  = aout + aout_us;              // [2][256][128] bf16
        float* bias2  = (float*)(Wb + 65536);        // [2][256] f32
        ushort_t* WoB = (ushort_t*)(bias2 + 512);    // [2][128][128] bf16

        k_prep<<<dim3(12), 256, 0, stream>>>(WpL, WpR, bpL, bpR, WoL, WoR,
                                             nw, nb, Wb, bias2, WoB);
        k_ln_proj<<<dim3(512, 2), 512, 0, stream>>>(featL, featR, Wb, bias2, kvL, kvR);
        k_attn<1><<<dim3(4096), 512, 0, stream>>>(kvL, kvR, out, aout);
        k_outproj_fast<<<dim3(512, 2), 512, 0, stream>>>(out, aout, featL, featR,
                                                         WoB, boL, boR);
    } else {
        // fallback: Wb/bias2 in d_out is safe here — its only reader
        // (k_ln_proj) finishes before the first d_out writer (k_attn<0>)
        ushort_t* Wb  = (ushort_t*)d_out;            // [2][256][128] bf16
        float* bias2  = (float*)d_out + 32768;       // [2][256] f32
        ushort_t* WoB = (ushort_t*)d_out + 66560;    // written, never read

        k_prep<<<dim3(12), 256, 0, stream>>>(WpL, WpR, bpL, bpR, WoL, WoR,
                                             nw, nb, Wb, bias2, WoB);
        k_ln_proj<<<dim3(512, 2), 512, 0, stream>>>(featL, featR, Wb, bias2, kvL, kvR);
        k_attn<0><<<dim3(4096), 512, 0, stream>>>(kvL, kvR, out, aout);
        k_outproj_slow<<<dim3(TOK / 64, 2), 512, 0, stream>>>(out, featL, featR,
                                                              WoL, WoR, boL, boR);
    }
}